// Round 10
// baseline (109.763 us; speedup 1.0000x reference)
//
#include <hip/hip_runtime.h>
#include <math.h>

typedef float f32x4 __attribute__((ext_vector_type(4)));
typedef __bf16 bf16x8 __attribute__((ext_vector_type(8)));
typedef unsigned short u16x8 __attribute__((ext_vector_type(8)));

__device__ __forceinline__ unsigned short f2bf(float f) {
    union { float f; unsigned int u; } v; v.f = f;
    unsigned int u = v.u;
    return (unsigned short)((u + 0x7fffu + ((u >> 16) & 1u)) >> 16);  // RNE
}
__device__ __forceinline__ float bf_lo(unsigned int d) {
    union { unsigned int u; float f; } v; v.u = d << 16; return v.f;
}
__device__ __forceinline__ float bf_hi(unsigned int d) {
    union { unsigned int u; float f; } v; v.u = d & 0xffff0000u; return v.f;
}
__device__ __forceinline__ float sigmoidf_(float v) {
    return 1.f / (1.f + __expf(-v));
}

// ---------------------------------------------------------------------------
// Kernel 1: MERGED left+right GEMM + x->bf16 conversion + uR reduction.
// Combined block (c = k/j-tile 0..3, e = e-tile 0..7) stages the x^T tile
// ONCE and uses it as A (left: Lp[k,e]) and B (right: R[e,j]) — halves x
// reads and staging vs the old separate left/right blocks. MFMA total
// unchanged (8/wave/kk).
//  left epi : LpT[b][i>>2][e][i&3] = C + b_lin[e]  (fp32, i-tile-blocked T)
//  right epi: R2[b][(e>>3)*2048 + j*8 + (e&7)] = bf16(C), PLUS per-fragment
//             uR partial: uRb[b][j] += sum_e a[e]*R[e,j] via atomicAdd
//             (deterministic per-fragment reduce; atomic order noise ~1e-5,
//             threshold margin 3x; uRb memset 0 per launch).
//  conv (t>=32): xbf = bf16(x)
// ---------------------------------------------------------------------------
__global__ __launch_bounds__(256) void mfma_gemm_kernel(
    const float* __restrict__ x,      // (8,256,256) x[b][w][k]
    const float* __restrict__ W,      // (512,512)
    const float* __restrict__ b_lin,  // (512)
    const float* __restrict__ a,      // (512)
    float* __restrict__ LpT,          // (8,64,512,4) fp32  L^T blocked
    unsigned short* __restrict__ R2,  // (8, 512e x 256j packed)
    unsigned short* __restrict__ xbf, // (8,256,256) bf16
    float* __restrict__ uRb)          // (8,256) fp32, zeroed per launch
{
    const int b = blockIdx.y;
    const int t = blockIdx.x;

    if (t >= 32) {   // ---- x -> bf16 straight conversion
        const int idx = b * 65536 + (t - 32) * 2048 + threadIdx.x * 8;
        const float4 v0 = *(const float4*)(x + idx);
        const float4 v1 = *(const float4*)(x + idx + 4);
        u16x8 o;
        o[0] = f2bf(v0.x); o[1] = f2bf(v0.y); o[2] = f2bf(v0.z); o[3] = f2bf(v0.w);
        o[4] = f2bf(v1.x); o[5] = f2bf(v1.y); o[6] = f2bf(v1.z); o[7] = f2bf(v1.w);
        *(u16x8*)(xbf + idx) = o;
        return;
    }

    const int c  = t & 3;            // shared k/j tile 0..3
    const int e  = t >> 2;           // e tile 0..7
    const int c0 = c * 64;
    const int e0 = e * 64;

    __shared__ unsigned short Ts[64][72];   // x^T tile [col-idx][w]
    __shared__ unsigned short Dl[64][72];   // W left  [e][k]
    __shared__ unsigned short Dr[64][72];   // W right [e][k]

    const int tid  = threadIdx.x;
    const int wv   = tid >> 6;
    const int lane = tid & 63;
    const int wy = wv >> 1, wx = wv & 1;
    const int lr = lane & 15;
    const int lk = lane >> 4;

    const float* xb = x + b * 65536;

    f32x4 accl[2][2], accr[2][2];
    #pragma unroll
    for (int i = 0; i < 2; i++)
        #pragma unroll
        for (int jj = 0; jj < 2; jj++) {
            accl[i][jj] = (f32x4){0.f, 0.f, 0.f, 0.f};
            accr[i][jj] = (f32x4){0.f, 0.f, 0.f, 0.f};
        }

    const int wl = tid >> 4;         // 0..15
    const int kg = tid & 15;         // 0..15
    const int dr = tid >> 2;         // 0..63
    const int dc = (tid & 3) * 16;

    for (int k0 = 0; k0 < 256; k0 += 64) {
        #pragma unroll
        for (int p = 0; p < 4; p++) {
            const int w = wl + 16 * p;
            const float4 v = *(const float4*)(xb + (k0 + w) * 256 + c0 + kg * 4);
            Ts[kg * 4 + 0][w] = f2bf(v.x);
            Ts[kg * 4 + 1][w] = f2bf(v.y);
            Ts[kg * 4 + 2][w] = f2bf(v.z);
            Ts[kg * 4 + 3][w] = f2bf(v.w);
        }
        {
            const float* srcl = W + (e0 + dr) * 512 + k0 + dc;
            const float4 v0 = *(const float4*)(srcl);
            const float4 v1 = *(const float4*)(srcl + 4);
            const float4 v2 = *(const float4*)(srcl + 8);
            const float4 v3 = *(const float4*)(srcl + 12);
            u16x8 o0, o1;
            o0[0]=f2bf(v0.x); o0[1]=f2bf(v0.y); o0[2]=f2bf(v0.z); o0[3]=f2bf(v0.w);
            o0[4]=f2bf(v1.x); o0[5]=f2bf(v1.y); o0[6]=f2bf(v1.z); o0[7]=f2bf(v1.w);
            o1[0]=f2bf(v2.x); o1[1]=f2bf(v2.y); o1[2]=f2bf(v2.z); o1[3]=f2bf(v2.w);
            o1[4]=f2bf(v3.x); o1[5]=f2bf(v3.y); o1[6]=f2bf(v3.z); o1[7]=f2bf(v3.w);
            *(u16x8*)&Dl[dr][dc]     = o0;
            *(u16x8*)&Dl[dr][dc + 8] = o1;
            const float* srcr = srcl + 256;
            const float4 w0 = *(const float4*)(srcr);
            const float4 w1 = *(const float4*)(srcr + 4);
            const float4 w2 = *(const float4*)(srcr + 8);
            const float4 w3 = *(const float4*)(srcr + 12);
            u16x8 q0, q1;
            q0[0]=f2bf(w0.x); q0[1]=f2bf(w0.y); q0[2]=f2bf(w0.z); q0[3]=f2bf(w0.w);
            q0[4]=f2bf(w1.x); q0[5]=f2bf(w1.y); q0[6]=f2bf(w1.z); q0[7]=f2bf(w1.w);
            q1[0]=f2bf(w2.x); q1[1]=f2bf(w2.y); q1[2]=f2bf(w2.z); q1[3]=f2bf(w2.w);
            q1[4]=f2bf(w3.x); q1[5]=f2bf(w3.y); q1[6]=f2bf(w3.z); q1[7]=f2bf(w3.w);
            *(u16x8*)&Dr[dr][dc]     = q0;
            *(u16x8*)&Dr[dr][dc + 8] = q1;
        }
        __syncthreads();
        #pragma unroll
        for (int kk = 0; kk < 64; kk += 32) {
            const bf16x8 t0 = *(const bf16x8*)&Ts[wy * 32 + lr][kk + lk * 8];
            const bf16x8 t1 = *(const bf16x8*)&Ts[wy * 32 + 16 + lr][kk + lk * 8];
            const bf16x8 l0 = *(const bf16x8*)&Dl[wx * 32 + lr][kk + lk * 8];
            const bf16x8 l1 = *(const bf16x8*)&Dl[wx * 32 + 16 + lr][kk + lk * 8];
            accl[0][0] = __builtin_amdgcn_mfma_f32_16x16x32_bf16(t0, l0, accl[0][0], 0, 0, 0);
            accl[0][1] = __builtin_amdgcn_mfma_f32_16x16x32_bf16(t0, l1, accl[0][1], 0, 0, 0);
            accl[1][0] = __builtin_amdgcn_mfma_f32_16x16x32_bf16(t1, l0, accl[1][0], 0, 0, 0);
            accl[1][1] = __builtin_amdgcn_mfma_f32_16x16x32_bf16(t1, l1, accl[1][1], 0, 0, 0);
            const bf16x8 r0 = *(const bf16x8*)&Dr[wy * 32 + lr][kk + lk * 8];
            const bf16x8 r1 = *(const bf16x8*)&Dr[wy * 32 + 16 + lr][kk + lk * 8];
            const bf16x8 s0 = *(const bf16x8*)&Ts[wx * 32 + lr][kk + lk * 8];
            const bf16x8 s1 = *(const bf16x8*)&Ts[wx * 32 + 16 + lr][kk + lk * 8];
            accr[0][0] = __builtin_amdgcn_mfma_f32_16x16x32_bf16(r0, s0, accr[0][0], 0, 0, 0);
            accr[0][1] = __builtin_amdgcn_mfma_f32_16x16x32_bf16(r0, s1, accr[0][1], 0, 0, 0);
            accr[1][0] = __builtin_amdgcn_mfma_f32_16x16x32_bf16(r1, s0, accr[1][0], 0, 0, 0);
            accr[1][1] = __builtin_amdgcn_mfma_f32_16x16x32_bf16(r1, s1, accr[1][1], 0, 0, 0);
        }
        __syncthreads();
    }

    // C/D layout: col = lane&15, row = (lane>>4)*4 + reg
    // ---- left epilogue: m = k (c-tile), n = e
    #pragma unroll
    for (int mi = 0; mi < 2; mi++) {
        #pragma unroll
        for (int ni = 0; ni < 2; ni++) {
            const int row = c0 + wy * 32 + mi * 16 + lk * 4;   // i (=k)
            const int col = e0 + wx * 32 + ni * 16 + lr;       // e
            const float bl = b_lin[col];
            float4 o;
            o.x = accl[mi][ni][0] + bl;
            o.y = accl[mi][ni][1] + bl;
            o.z = accl[mi][ni][2] + bl;
            o.w = accl[mi][ni][3] + bl;
            *(float4*)(LpT + b * 131072 + (row >> 2) * 2048 + col * 4) = o;
        }
    }
    // ---- right epilogue: m = e, n = j (c-tile); + uR fragment reduction
    {
        unsigned short* R2b = R2 + b * 131072;
        float pj[2] = {0.f, 0.f};
        int colj[2];
        #pragma unroll
        for (int ni = 0; ni < 2; ni++) {
            colj[ni] = c0 + wx * 32 + ni * 16 + lr;            // j
            #pragma unroll
            for (int mi = 0; mi < 2; mi++) {
                const int row = e0 + wy * 32 + mi * 16 + lk * 4;   // e base (4)
                ushort4 o;
                o.x = f2bf(accr[mi][ni][0]);
                o.y = f2bf(accr[mi][ni][1]);
                o.z = f2bf(accr[mi][ni][2]);
                o.w = f2bf(accr[mi][ni][3]);
                *(ushort4*)(R2b + (row >> 3) * 2048 + colj[ni] * 8 + (row & 7)) = o;
                pj[ni] += a[row + 0] * accr[mi][ni][0]
                        + a[row + 1] * accr[mi][ni][1]
                        + a[row + 2] * accr[mi][ni][2]
                        + a[row + 3] * accr[mi][ni][3];
            }
        }
        atomicAdd(&uRb[b * 256 + colj[0]], pj[0]);
        atomicAdd(&uRb[b * 256 + colj[1]], pj[1]);
    }
}

// ---------------------------------------------------------------------------
// Kernel 2 (r9 structure, best measured 98.6 total, minus the redundant
// rsum): grid 512 = (i-tile of 4) x (b = blk&7); 1024 thr = 256 j x 4 e-q.
// uR[b][j] now precomputed by K1 (was recomputed 64x here); score loop drops
// the rsum FMA chain and rgp LDS entirely (-10% score VALU).
// Load-hoists (r9, proven): matvec x-fragments kt0..3, bias, and now uR
// loaded BEFORE the post-score barrier.
// score[i][j] = 0.6*(uL[i]+uR[j]) + 0.4*sum_e a[e]*|L[i,e]+R[e,j]| + bias
// ---------------------------------------------------------------------------
__global__ __launch_bounds__(1024, 8) void attn_kernel(
    const unsigned short* __restrict__ xbf,   // (8,256,256) bf16 x[b][w][j]
    const float* __restrict__ LpT,            // (8,64,512,4) fp32, b_lin folded
    const unsigned int* __restrict__ R2u,     // packed bf16 pairs
    const float* __restrict__ a,              // (512)
    const float* __restrict__ bias,           // (256,256)
    const float* __restrict__ uRb,            // (8,256) from K1
    float* __restrict__ out)                  // (8,256,256)
{
    const int b     = blockIdx.x & 7;
    const int itile = blockIdx.x >> 3;        // 0..63
    const int i0    = itile * 4;
    const int tid   = threadIdx.x;
    const int j     = tid & 255;
    const int wv    = tid >> 6;               // 0..15
    const int lane  = tid & 63;

    __shared__ float acc2P[4][4][256];        // 16 KB  [e-quarter][i][j]
    __shared__ float u15p[8][4];
    __shared__ unsigned short atbf[16 * 264]; // 8.25 KB (rows 4..15 unused)

    // wave-uniform e-quarter index (readfirstlane -> SGPR -> scalar loads)
    const int ehq = __builtin_amdgcn_readfirstlane(tid >> 8);  // 0..3

    // uniform stream bases
    const float* Lq = LpT + b * 131072 + itile * 2048 + ehq * 512;  // [e_loc][4]
    const float* aq = a + ehq * 128;
    const uint4* Rq = (const uint4*)(R2u + b * 65536) + (ehq * 16) * 256 + j;

    // ---- R prefetch, depth 2 (named regs, no dynamic indexing)
    uint4 rb0 = Rq[0];
    uint4 rb1 = Rq[256];

    // ---- uL partials: waves 0..7; waves 8..15 go straight to score
    if (tid < 512) {
        const float4 lv = *(const float4*)(LpT + b * 131072 + itile * 2048 + tid * 4);
        const float ae = a[tid];
        float p0 = ae * lv.x, p1 = ae * lv.y, p2 = ae * lv.z, p3 = ae * lv.w;
        #pragma unroll
        for (int off = 32; off; off >>= 1) {
            p0 += __shfl_xor(p0, off);
            p1 += __shfl_xor(p1, off);
            p2 += __shfl_xor(p2, off);
            p3 += __shfl_xor(p3, off);
        }
        if (lane == 0) {
            u15p[wv][0] = p0; u15p[wv][1] = p1;
            u15p[wv][2] = p2; u15p[wv][3] = p3;
        }
    }

    // ---- score: 128 e per thread (e-quarter), 4 i rows, uniform L/a loads
    float acc0 = 0.f, acc1 = 0.f, acc2 = 0.f, acc3 = 0.f;

    #pragma unroll 2
    for (int tk = 0; tk < 16; tk++) {
        uint4 rb2;
        if (tk < 14) rb2 = Rq[(tk + 2) * 256];
        float r[8];
        r[0] = bf_lo(rb0.x); r[1] = bf_hi(rb0.x);
        r[2] = bf_lo(rb0.y); r[3] = bf_hi(rb0.y);
        r[4] = bf_lo(rb0.z); r[5] = bf_hi(rb0.z);
        r[6] = bf_lo(rb0.w); r[7] = bf_hi(rb0.w);
        #pragma unroll
        for (int g = 0; g < 2; g++) {
            const float4 av4 = *(const float4*)(aq + tk * 8 + g * 4);
            const float4 l0 = *(const float4*)(Lq + (tk * 8 + g * 4 + 0) * 4);
            const float4 l1 = *(const float4*)(Lq + (tk * 8 + g * 4 + 1) * 4);
            const float4 l2 = *(const float4*)(Lq + (tk * 8 + g * 4 + 2) * 4);
            const float4 l3 = *(const float4*)(Lq + (tk * 8 + g * 4 + 3) * 4);
            const float rv0 = r[g * 4 + 0];
            const float rv1 = r[g * 4 + 1];
            const float rv2 = r[g * 4 + 2];
            const float rv3 = r[g * 4 + 3];
            acc0 = fmaf(av4.x, fabsf(l0.x + rv0), acc0);
            acc1 = fmaf(av4.x, fabsf(l0.y + rv0), acc1);
            acc2 = fmaf(av4.x, fabsf(l0.z + rv0), acc2);
            acc3 = fmaf(av4.x, fabsf(l0.w + rv0), acc3);
            acc0 = fmaf(av4.y, fabsf(l1.x + rv1), acc0);
            acc1 = fmaf(av4.y, fabsf(l1.y + rv1), acc1);
            acc2 = fmaf(av4.y, fabsf(l1.z + rv1), acc2);
            acc3 = fmaf(av4.y, fabsf(l1.w + rv1), acc3);
            acc0 = fmaf(av4.z, fabsf(l2.x + rv2), acc0);
            acc1 = fmaf(av4.z, fabsf(l2.y + rv2), acc1);
            acc2 = fmaf(av4.z, fabsf(l2.z + rv2), acc2);
            acc3 = fmaf(av4.z, fabsf(l2.w + rv2), acc3);
            acc0 = fmaf(av4.w, fabsf(l3.x + rv3), acc0);
            acc1 = fmaf(av4.w, fabsf(l3.y + rv3), acc1);
            acc2 = fmaf(av4.w, fabsf(l3.z + rv3), acc2);
            acc3 = fmaf(av4.w, fabsf(l3.w + rv3), acc3);
        }
        rb0 = rb1;
        rb1 = rb2;
    }
    acc2P[ehq][0][j] = acc0;
    acc2P[ehq][1][j] = acc1;
    acc2P[ehq][2][j] = acc2;
    acc2P[ehq][3][j] = acc3;

    // ---- hoists (r9, proven): matvec x-fragments kt0..3, bias, uR loads
    // issued above the barrier; latency hides under drain + softmax.
    const int lr = lane & 15;
    const int lk = lane >> 4;
    const unsigned short* xw = xbf + b * 65536 + (wv * 16 + lr) * 256;
    const bf16x8 px0 = *(const bf16x8*)(xw + 0 * 32 + lk * 8);
    const bf16x8 px1 = *(const bf16x8*)(xw + 1 * 32 + lk * 8);
    const bf16x8 px2 = *(const bf16x8*)(xw + 2 * 32 + lk * 8);
    const bf16x8 px3 = *(const bf16x8*)(xw + 3 * 32 + lk * 8);

    float bs0 = 0.f, bs1 = 0.f, bs2 = 0.f, bs3 = 0.f;
    float ur0 = 0.f, ur1 = 0.f, ur2 = 0.f, ur3 = 0.f;
    if (wv < 4) {
        const float* brow = bias + (i0 + wv) * 256 + lane;
        bs0 = brow[0];
        bs1 = brow[64];
        bs2 = brow[128];
        bs3 = brow[192];
        const float* urow = uRb + b * 256 + lane;
        ur0 = urow[0];
        ur1 = urow[64];
        ur2 = urow[128];
        ur3 = urow[192];
    }
    __syncthreads();

    // ---- softmax (combine folded in): wave i (wv<4) -> row i
    if (wv < 4) {
        const int i = wv;
        float u15 = 0.f;
        #pragma unroll
        for (int q = 0; q < 8; q++) u15 += u15p[q][i];   // LDS broadcast reads
        u15 *= 0.6f;
        float v[4];
        const float bsv[4] = { bs0, bs1, bs2, bs3 };
        const float urv[4] = { ur0, ur1, ur2, ur3 };
        float m = -1e30f;
        #pragma unroll
        for (int u = 0; u < 4; u++) {
            const int jj = lane + 64 * u;
            const float ab = acc2P[0][i][jj] + acc2P[1][i][jj]
                           + acc2P[2][i][jj] + acc2P[3][i][jj];
            v[u] = u15 + 0.6f * urv[u] + 0.4f * ab + bsv[u];
            m = fmaxf(m, v[u]);
        }
        #pragma unroll
        for (int off = 32; off; off >>= 1) m = fmaxf(m, __shfl_xor(m, off));
        float ssum = 0.f;
        #pragma unroll
        for (int u = 0; u < 4; u++) { v[u] = __expf(v[u] - m); ssum += v[u]; }
        #pragma unroll
        for (int off = 32; off; off >>= 1) ssum += __shfl_xor(ssum, off);
        const float inv = 1.f / ssum;
        #pragma unroll
        for (int u = 0; u < 4; u++)
            atbf[i * 264 + lane + 64 * u] = f2bf(v[u] * inv);
    }
    __syncthreads();

    // ---- matvec via MFMA: D[i][w] = sum_j attn[i][j] * x[b][w][j]
    // 16 waves; wave wv handles w-tile wv. atbf rows 4..15 are garbage LDS
    // but only pollute D rows 4..15, which are never stored (lk==0 only).
    {
        f32x4 hacc = (f32x4){0.f, 0.f, 0.f, 0.f};
        const bf16x8 a0 = *(const bf16x8*)&atbf[lr * 264 + 0 * 32 + lk * 8];
        hacc = __builtin_amdgcn_mfma_f32_16x16x32_bf16(a0, px0, hacc, 0, 0, 0);
        const bf16x8 a1 = *(const bf16x8*)&atbf[lr * 264 + 1 * 32 + lk * 8];
        hacc = __builtin_amdgcn_mfma_f32_16x16x32_bf16(a1, px1, hacc, 0, 0, 0);
        const bf16x8 a2 = *(const bf16x8*)&atbf[lr * 264 + 2 * 32 + lk * 8];
        hacc = __builtin_amdgcn_mfma_f32_16x16x32_bf16(a2, px2, hacc, 0, 0, 0);
        const bf16x8 a3 = *(const bf16x8*)&atbf[lr * 264 + 3 * 32 + lk * 8];
        hacc = __builtin_amdgcn_mfma_f32_16x16x32_bf16(a3, px3, hacc, 0, 0, 0);
        #pragma unroll
        for (int kt = 4; kt < 8; kt++) {
            const bf16x8 av = *(const bf16x8*)&atbf[lr * 264 + kt * 32 + lk * 8];
            const bf16x8 bv = *(const bf16x8*)(xw + kt * 32 + lk * 8);
            hacc = __builtin_amdgcn_mfma_f32_16x16x32_bf16(av, bv, hacc, 0, 0, 0);
        }
        if (lk == 0) {
            float4 o;
            o.x = sigmoidf_(hacc[0]);
            o.y = sigmoidf_(hacc[1]);
            o.z = sigmoidf_(hacc[2]);
            o.w = sigmoidf_(hacc[3]);
            *(float4*)(out + b * 65536 + (wv * 16 + lr) * 256 + i0) = o;
        }
    }
}

extern "C" void kernel_launch(void* const* d_in, const int* in_sizes, int n_in,
                              void* d_out, int out_size, void* d_ws, size_t ws_size,
                              hipStream_t stream) {
    const float* x     = (const float*)d_in[0];
    const float* W     = (const float*)d_in[1];
    const float* b_lin = (const float*)d_in[2];
    const float* a     = (const float*)d_in[3];
    const float* bias  = (const float*)d_in[4];
    float* out = (float*)d_out;

    char* ws = (char*)d_ws;
    float*          LpT = (float*)ws;                          // 4 MB
    unsigned short* R2  = (unsigned short*)(ws + (4 << 20));   // 2 MB
    unsigned short* xbf = (unsigned short*)(ws + (6 << 20));   // 1 MB
    float*          uRb = (float*)(ws + (7 << 20));            // 8 KB

    hipMemsetAsync(uRb, 0, 8 * 256 * sizeof(float), stream);
    mfma_gemm_kernel<<<dim3(64, 8), 256, 0, stream>>>(x, W, b_lin, a,
                                                      LpT, R2, xbf, uRb);
    attn_kernel<<<512, 1024, 0, stream>>>(xbf, LpT, (const unsigned int*)R2,
                                          a, bias, uRb, out);
}

// Round 11
// 104.103 us; speedup vs baseline: 1.0544x; 1.0544x over previous
//
#include <hip/hip_runtime.h>
#include <math.h>

typedef float f32x4 __attribute__((ext_vector_type(4)));
typedef __bf16 bf16x8 __attribute__((ext_vector_type(8)));
typedef unsigned short u16x8 __attribute__((ext_vector_type(8)));

__device__ __forceinline__ unsigned short f2bf(float f) {
    union { float f; unsigned int u; } v; v.f = f;
    unsigned int u = v.u;
    return (unsigned short)((u + 0x7fffu + ((u >> 16) & 1u)) >> 16);  // RNE
}
__device__ __forceinline__ float bf_lo(unsigned int d) {
    union { unsigned int u; float f; } v; v.u = d << 16; return v.f;
}
__device__ __forceinline__ float bf_hi(unsigned int d) {
    union { unsigned int u; float f; } v; v.u = d & 0xffff0000u; return v.f;
}
__device__ __forceinline__ float sigmoidf_(float v) {
    return 1.f / (1.f + __expf(-v));
}

// ---------------------------------------------------------------------------
// Kernel 1 (r9 structure verbatim — separate left/right blocks, 2-3 blocks/CU
// proven; r10's merged variant halved block parallelism and regressed 11us).
// ONLY addition vs r9: right-block epilogue also reduces its C-fragments
// against a[e] and atomicAdds into uRb[b][j] (16 FMA + 2 atomics/thread,
// epilogue-only; numerics proven in r10, absmax 0.00390625).
//  left  (t<32):  -> LpT[b][i>>2][e][i&3] = C + b_lin[e]   (fp32 transposed)
//  right (32<=t<64): -> R2[...] = bf16(C); uRb[b][j] += sum_e a[e]*C[e,j]
//  conv  (t>=64): xbf = bf16(x)
// ---------------------------------------------------------------------------
__global__ __launch_bounds__(256) void mfma_gemm_kernel(
    const float* __restrict__ x,      // (8,256,256) x[b][w][k]
    const float* __restrict__ W,      // (512,512)
    const float* __restrict__ b_lin,  // (512)
    const float* __restrict__ a,      // (512)
    float* __restrict__ LpT,          // (8,64,512,4) fp32  L^T blocked
    unsigned short* __restrict__ R2,  // (8, 512e x 256j packed)
    unsigned short* __restrict__ xbf, // (8,256,256) bf16
    float* __restrict__ uRb)          // (8,256) fp32, zeroed per launch
{
    const int b = blockIdx.y;
    const int t = blockIdx.x;

    if (t >= 64) {   // ---- x -> bf16 straight conversion
        const int idx = b * 65536 + (t - 64) * 2048 + threadIdx.x * 8;
        const float4 v0 = *(const float4*)(x + idx);
        const float4 v1 = *(const float4*)(x + idx + 4);
        u16x8 o;
        o[0] = f2bf(v0.x); o[1] = f2bf(v0.y); o[2] = f2bf(v0.z); o[3] = f2bf(v0.w);
        o[4] = f2bf(v1.x); o[5] = f2bf(v1.y); o[6] = f2bf(v1.z); o[7] = f2bf(v1.w);
        *(u16x8*)(xbf + idx) = o;
        return;
    }

    const bool left = (t < 32);
    int m0, n0;
    if (left) { m0 = (t >> 3) * 64; n0 = (t & 7) * 64; }
    else      { const int tt = t - 32; m0 = (tt >> 2) * 64; n0 = (tt & 3) * 64; }

    __shared__ unsigned short As[64][72];
    __shared__ unsigned short Bs[64][72];

    unsigned short (*Ts)[72] = left ? As : Bs;   // x^T tile
    unsigned short (*Ds)[72] = left ? Bs : As;   // W tile
    const int cbase = left ? m0 : n0;            // x column base (k or j)
    const int rbase = left ? n0 : m0;            // W row base (e)
    const int coff  = left ? 0 : 256;            // W column offset

    const int tid  = threadIdx.x;
    const int wv   = tid >> 6;
    const int lane = tid & 63;
    const int wy = wv >> 1, wx = wv & 1;
    const int lr = lane & 15;
    const int lk = lane >> 4;

    const float* xb = x + b * 65536;

    f32x4 acc[2][2];
    #pragma unroll
    for (int i = 0; i < 2; i++)
        #pragma unroll
        for (int jj = 0; jj < 2; jj++) acc[i][jj] = (f32x4){0.f, 0.f, 0.f, 0.f};

    const int wl = tid >> 4;         // 0..15
    const int kg = tid & 15;         // 0..15
    const int dr = tid >> 2;         // 0..63
    const int dc = (tid & 3) * 16;

    for (int k0 = 0; k0 < 256; k0 += 64) {
        #pragma unroll
        for (int p = 0; p < 4; p++) {
            const int w = wl + 16 * p;
            const float4 v = *(const float4*)(xb + (k0 + w) * 256 + cbase + kg * 4);
            Ts[kg * 4 + 0][w] = f2bf(v.x);
            Ts[kg * 4 + 1][w] = f2bf(v.y);
            Ts[kg * 4 + 2][w] = f2bf(v.z);
            Ts[kg * 4 + 3][w] = f2bf(v.w);
        }
        {
            const float* src = W + (rbase + dr) * 512 + coff + k0 + dc;
            const float4 v0 = *(const float4*)(src);
            const float4 v1 = *(const float4*)(src + 4);
            const float4 v2 = *(const float4*)(src + 8);
            const float4 v3 = *(const float4*)(src + 12);
            u16x8 o0, o1;
            o0[0]=f2bf(v0.x); o0[1]=f2bf(v0.y); o0[2]=f2bf(v0.z); o0[3]=f2bf(v0.w);
            o0[4]=f2bf(v1.x); o0[5]=f2bf(v1.y); o0[6]=f2bf(v1.z); o0[7]=f2bf(v1.w);
            o1[0]=f2bf(v2.x); o1[1]=f2bf(v2.y); o1[2]=f2bf(v2.z); o1[3]=f2bf(v2.w);
            o1[4]=f2bf(v3.x); o1[5]=f2bf(v3.y); o1[6]=f2bf(v3.z); o1[7]=f2bf(v3.w);
            *(u16x8*)&Ds[dr][dc]     = o0;
            *(u16x8*)&Ds[dr][dc + 8] = o1;
        }
        __syncthreads();
        #pragma unroll
        for (int kk = 0; kk < 64; kk += 32) {
            const bf16x8 a0 = *(const bf16x8*)&As[wy * 32 + lr][kk + lk * 8];
            const bf16x8 a1 = *(const bf16x8*)&As[wy * 32 + 16 + lr][kk + lk * 8];
            const bf16x8 b0 = *(const bf16x8*)&Bs[wx * 32 + lr][kk + lk * 8];
            const bf16x8 b1 = *(const bf16x8*)&Bs[wx * 32 + 16 + lr][kk + lk * 8];
            acc[0][0] = __builtin_amdgcn_mfma_f32_16x16x32_bf16(a0, b0, acc[0][0], 0, 0, 0);
            acc[0][1] = __builtin_amdgcn_mfma_f32_16x16x32_bf16(a0, b1, acc[0][1], 0, 0, 0);
            acc[1][0] = __builtin_amdgcn_mfma_f32_16x16x32_bf16(a1, b0, acc[1][0], 0, 0, 0);
            acc[1][1] = __builtin_amdgcn_mfma_f32_16x16x32_bf16(a1, b1, acc[1][1], 0, 0, 0);
        }
        __syncthreads();
    }

    // C/D layout: col = lane&15, row = (lane>>4)*4 + reg
    if (left) {
        #pragma unroll
        for (int mi = 0; mi < 2; mi++) {
            #pragma unroll
            for (int ni = 0; ni < 2; ni++) {
                const int row = m0 + wy * 32 + mi * 16 + lk * 4;   // i (=k)
                const int col = n0 + wx * 32 + ni * 16 + lr;       // e
                const float bl = b_lin[col];
                float4 o;
                o.x = acc[mi][ni][0] + bl;
                o.y = acc[mi][ni][1] + bl;
                o.z = acc[mi][ni][2] + bl;
                o.w = acc[mi][ni][3] + bl;
                *(float4*)(LpT + b * 131072 + (row >> 2) * 2048 + col * 4) = o;
            }
        }
    } else {
        unsigned short* R2b = R2 + b * 131072;
        float pj[2] = {0.f, 0.f};
        int colj[2];
        #pragma unroll
        for (int ni = 0; ni < 2; ni++) {
            colj[ni] = n0 + wx * 32 + ni * 16 + lr;                // j
            #pragma unroll
            for (int mi = 0; mi < 2; mi++) {
                const int row = m0 + wy * 32 + mi * 16 + lk * 4;   // e base (4)
                ushort4 o;
                o.x = f2bf(acc[mi][ni][0]);
                o.y = f2bf(acc[mi][ni][1]);
                o.z = f2bf(acc[mi][ni][2]);
                o.w = f2bf(acc[mi][ni][3]);
                *(ushort4*)(R2b + (row >> 3) * 2048 + colj[ni] * 8 + (row & 7)) = o;
                pj[ni] += a[row + 0] * acc[mi][ni][0]
                        + a[row + 1] * acc[mi][ni][1]
                        + a[row + 2] * acc[mi][ni][2]
                        + a[row + 3] * acc[mi][ni][3];
            }
        }
        atomicAdd(&uRb[b * 256 + colj[0]], pj[0]);
        atomicAdd(&uRb[b * 256 + colj[1]], pj[1]);
    }
}

// ---------------------------------------------------------------------------
// Kernel 2 (r10 attn verbatim — rsum chain and rgp LDS deleted, uR from K1):
// grid 512 = (i-tile of 4) x (b = blk&7); 1024 thr = 256 j x 4 e-quarters.
// Load-hoists (r9, proven): matvec x-fragments kt0..3, bias, uR loaded
// BEFORE the post-score barrier.
// score[i][j] = 0.6*(uL[i]+uR[j]) + 0.4*sum_e a[e]*|L[i,e]+R[e,j]| + bias
// ---------------------------------------------------------------------------
__global__ __launch_bounds__(1024, 8) void attn_kernel(
    const unsigned short* __restrict__ xbf,   // (8,256,256) bf16 x[b][w][j]
    const float* __restrict__ LpT,            // (8,64,512,4) fp32, b_lin folded
    const unsigned int* __restrict__ R2u,     // packed bf16 pairs
    const float* __restrict__ a,              // (512)
    const float* __restrict__ bias,           // (256,256)
    const float* __restrict__ uRb,            // (8,256) from K1
    float* __restrict__ out)                  // (8,256,256)
{
    const int b     = blockIdx.x & 7;
    const int itile = blockIdx.x >> 3;        // 0..63
    const int i0    = itile * 4;
    const int tid   = threadIdx.x;
    const int j     = tid & 255;
    const int wv    = tid >> 6;               // 0..15
    const int lane  = tid & 63;

    __shared__ float acc2P[4][4][256];        // 16 KB  [e-quarter][i][j]
    __shared__ float u15p[8][4];
    __shared__ unsigned short atbf[16 * 264]; // 8.25 KB (rows 4..15 unused)

    // wave-uniform e-quarter index (readfirstlane -> SGPR -> scalar loads)
    const int ehq = __builtin_amdgcn_readfirstlane(tid >> 8);  // 0..3

    // uniform stream bases
    const float* Lq = LpT + b * 131072 + itile * 2048 + ehq * 512;  // [e_loc][4]
    const float* aq = a + ehq * 128;
    const uint4* Rq = (const uint4*)(R2u + b * 65536) + (ehq * 16) * 256 + j;

    // ---- R prefetch, depth 2 (named regs, no dynamic indexing)
    uint4 rb0 = Rq[0];
    uint4 rb1 = Rq[256];

    // ---- uL partials: waves 0..7; waves 8..15 go straight to score
    if (tid < 512) {
        const float4 lv = *(const float4*)(LpT + b * 131072 + itile * 2048 + tid * 4);
        const float ae = a[tid];
        float p0 = ae * lv.x, p1 = ae * lv.y, p2 = ae * lv.z, p3 = ae * lv.w;
        #pragma unroll
        for (int off = 32; off; off >>= 1) {
            p0 += __shfl_xor(p0, off);
            p1 += __shfl_xor(p1, off);
            p2 += __shfl_xor(p2, off);
            p3 += __shfl_xor(p3, off);
        }
        if (lane == 0) {
            u15p[wv][0] = p0; u15p[wv][1] = p1;
            u15p[wv][2] = p2; u15p[wv][3] = p3;
        }
    }

    // ---- score: 128 e per thread (e-quarter), 4 i rows, uniform L/a loads
    float acc0 = 0.f, acc1 = 0.f, acc2 = 0.f, acc3 = 0.f;

    #pragma unroll 2
    for (int tk = 0; tk < 16; tk++) {
        uint4 rb2;
        if (tk < 14) rb2 = Rq[(tk + 2) * 256];
        float r[8];
        r[0] = bf_lo(rb0.x); r[1] = bf_hi(rb0.x);
        r[2] = bf_lo(rb0.y); r[3] = bf_hi(rb0.y);
        r[4] = bf_lo(rb0.z); r[5] = bf_hi(rb0.z);
        r[6] = bf_lo(rb0.w); r[7] = bf_hi(rb0.w);
        #pragma unroll
        for (int g = 0; g < 2; g++) {
            const float4 av4 = *(const float4*)(aq + tk * 8 + g * 4);
            const float4 l0 = *(const float4*)(Lq + (tk * 8 + g * 4 + 0) * 4);
            const float4 l1 = *(const float4*)(Lq + (tk * 8 + g * 4 + 1) * 4);
            const float4 l2 = *(const float4*)(Lq + (tk * 8 + g * 4 + 2) * 4);
            const float4 l3 = *(const float4*)(Lq + (tk * 8 + g * 4 + 3) * 4);
            const float rv0 = r[g * 4 + 0];
            const float rv1 = r[g * 4 + 1];
            const float rv2 = r[g * 4 + 2];
            const float rv3 = r[g * 4 + 3];
            acc0 = fmaf(av4.x, fabsf(l0.x + rv0), acc0);
            acc1 = fmaf(av4.x, fabsf(l0.y + rv0), acc1);
            acc2 = fmaf(av4.x, fabsf(l0.z + rv0), acc2);
            acc3 = fmaf(av4.x, fabsf(l0.w + rv0), acc3);
            acc0 = fmaf(av4.y, fabsf(l1.x + rv1), acc0);
            acc1 = fmaf(av4.y, fabsf(l1.y + rv1), acc1);
            acc2 = fmaf(av4.y, fabsf(l1.z + rv1), acc2);
            acc3 = fmaf(av4.y, fabsf(l1.w + rv1), acc3);
            acc0 = fmaf(av4.z, fabsf(l2.x + rv2), acc0);
            acc1 = fmaf(av4.z, fabsf(l2.y + rv2), acc1);
            acc2 = fmaf(av4.z, fabsf(l2.z + rv2), acc2);
            acc3 = fmaf(av4.z, fabsf(l2.w + rv2), acc3);
            acc0 = fmaf(av4.w, fabsf(l3.x + rv3), acc0);
            acc1 = fmaf(av4.w, fabsf(l3.y + rv3), acc1);
            acc2 = fmaf(av4.w, fabsf(l3.z + rv3), acc2);
            acc3 = fmaf(av4.w, fabsf(l3.w + rv3), acc3);
        }
        rb0 = rb1;
        rb1 = rb2;
    }
    acc2P[ehq][0][j] = acc0;
    acc2P[ehq][1][j] = acc1;
    acc2P[ehq][2][j] = acc2;
    acc2P[ehq][3][j] = acc3;

    // ---- hoists (r9, proven): matvec x-fragments kt0..3, bias, uR loads
    // issued above the barrier; latency hides under drain + softmax.
    const int lr = lane & 15;
    const int lk = lane >> 4;
    const unsigned short* xw = xbf + b * 65536 + (wv * 16 + lr) * 256;
    const bf16x8 px0 = *(const bf16x8*)(xw + 0 * 32 + lk * 8);
    const bf16x8 px1 = *(const bf16x8*)(xw + 1 * 32 + lk * 8);
    const bf16x8 px2 = *(const bf16x8*)(xw + 2 * 32 + lk * 8);
    const bf16x8 px3 = *(const bf16x8*)(xw + 3 * 32 + lk * 8);

    float bs0 = 0.f, bs1 = 0.f, bs2 = 0.f, bs3 = 0.f;
    float ur0 = 0.f, ur1 = 0.f, ur2 = 0.f, ur3 = 0.f;
    if (wv < 4) {
        const float* brow = bias + (i0 + wv) * 256 + lane;
        bs0 = brow[0];
        bs1 = brow[64];
        bs2 = brow[128];
        bs3 = brow[192];
        const float* urow = uRb + b * 256 + lane;
        ur0 = urow[0];
        ur1 = urow[64];
        ur2 = urow[128];
        ur3 = urow[192];
    }
    __syncthreads();

    // ---- softmax (combine folded in): wave i (wv<4) -> row i
    if (wv < 4) {
        const int i = wv;
        float u15 = 0.f;
        #pragma unroll
        for (int q = 0; q < 8; q++) u15 += u15p[q][i];   // LDS broadcast reads
        u15 *= 0.6f;
        float v[4];
        const float bsv[4] = { bs0, bs1, bs2, bs3 };
        const float urv[4] = { ur0, ur1, ur2, ur3 };
        float m = -1e30f;
        #pragma unroll
        for (int u = 0; u < 4; u++) {
            const int jj = lane + 64 * u;
            const float ab = acc2P[0][i][jj] + acc2P[1][i][jj]
                           + acc2P[2][i][jj] + acc2P[3][i][jj];
            v[u] = u15 + 0.6f * urv[u] + 0.4f * ab + bsv[u];
            m = fmaxf(m, v[u]);
        }
        #pragma unroll
        for (int off = 32; off; off >>= 1) m = fmaxf(m, __shfl_xor(m, off));
        float ssum = 0.f;
        #pragma unroll
        for (int u = 0; u < 4; u++) { v[u] = __expf(v[u] - m); ssum += v[u]; }
        #pragma unroll
        for (int off = 32; off; off >>= 1) ssum += __shfl_xor(ssum, off);
        const float inv = 1.f / ssum;
        #pragma unroll
        for (int u = 0; u < 4; u++)
            atbf[i * 264 + lane + 64 * u] = f2bf(v[u] * inv);
    }
    __syncthreads();

    // ---- matvec via MFMA: D[i][w] = sum_j attn[i][j] * x[b][w][j]
    // 16 waves; wave wv handles w-tile wv. atbf rows 4..15 are garbage LDS
    // but only pollute D rows 4..15, which are never stored (lk==0 only).
    {
        f32x4 hacc = (f32x4){0.f, 0.f, 0.f, 0.f};
        const bf16x8 a0 = *(const bf16x8*)&atbf[lr * 264 + 0 * 32 + lk * 8];
        hacc = __builtin_amdgcn_mfma_f32_16x16x32_bf16(a0, px0, hacc, 0, 0, 0);
        const bf16x8 a1 = *(const bf16x8*)&atbf[lr * 264 + 1 * 32 + lk * 8];
        hacc = __builtin_amdgcn_mfma_f32_16x16x32_bf16(a1, px1, hacc, 0, 0, 0);
        const bf16x8 a2 = *(const bf16x8*)&atbf[lr * 264 + 2 * 32 + lk * 8];
        hacc = __builtin_amdgcn_mfma_f32_16x16x32_bf16(a2, px2, hacc, 0, 0, 0);
        const bf16x8 a3 = *(const bf16x8*)&atbf[lr * 264 + 3 * 32 + lk * 8];
        hacc = __builtin_amdgcn_mfma_f32_16x16x32_bf16(a3, px3, hacc, 0, 0, 0);
        #pragma unroll
        for (int kt = 4; kt < 8; kt++) {
            const bf16x8 av = *(const bf16x8*)&atbf[lr * 264 + kt * 32 + lk * 8];
            const bf16x8 bv = *(const bf16x8*)(xw + kt * 32 + lk * 8);
            hacc = __builtin_amdgcn_mfma_f32_16x16x32_bf16(av, bv, hacc, 0, 0, 0);
        }
        if (lk == 0) {
            float4 o;
            o.x = sigmoidf_(hacc[0]);
            o.y = sigmoidf_(hacc[1]);
            o.z = sigmoidf_(hacc[2]);
            o.w = sigmoidf_(hacc[3]);
            *(float4*)(out + b * 65536 + (wv * 16 + lr) * 256 + i0) = o;
        }
    }
}

extern "C" void kernel_launch(void* const* d_in, const int* in_sizes, int n_in,
                              void* d_out, int out_size, void* d_ws, size_t ws_size,
                              hipStream_t stream) {
    const float* x     = (const float*)d_in[0];
    const float* W     = (const float*)d_in[1];
    const float* b_lin = (const float*)d_in[2];
    const float* a     = (const float*)d_in[3];
    const float* bias  = (const float*)d_in[4];
    float* out = (float*)d_out;

    char* ws = (char*)d_ws;
    float*          LpT = (float*)ws;                          // 4 MB
    unsigned short* R2  = (unsigned short*)(ws + (4 << 20));   // 2 MB
    unsigned short* xbf = (unsigned short*)(ws + (6 << 20));   // 1 MB
    float*          uRb = (float*)(ws + (7 << 20));            // 8 KB

    hipMemsetAsync(uRb, 0, 8 * 256 * sizeof(float), stream);
    mfma_gemm_kernel<<<dim3(96, 8), 256, 0, stream>>>(x, W, b_lin, a,
                                                      LpT, R2, xbf, uRb);
    attn_kernel<<<512, 1024, 0, stream>>>(xbf, LpT, (const unsigned int*)R2,
                                          a, bias, uRb, out);
}

// Round 13
// 98.835 us; speedup vs baseline: 1.1106x; 1.0533x over previous
//
#include <hip/hip_runtime.h>
#include <math.h>

typedef float f32x4 __attribute__((ext_vector_type(4)));
typedef __bf16 bf16x8 __attribute__((ext_vector_type(8)));
typedef unsigned short u16x8 __attribute__((ext_vector_type(8)));

__device__ __forceinline__ unsigned short f2bf(float f) {
    union { float f; unsigned int u; } v; v.f = f;
    unsigned int u = v.u;
    return (unsigned short)((u + 0x7fffu + ((u >> 16) & 1u)) >> 16);  // RNE
}
__device__ __forceinline__ float bf_lo(unsigned int d) {
    union { unsigned int u; float f; } v; v.u = d << 16; return v.f;
}
__device__ __forceinline__ float bf_hi(unsigned int d) {
    union { unsigned int u; float f; } v; v.u = d & 0xffff0000u; return v.f;
}
__device__ __forceinline__ float sigmoidf_(float v) {
    return 1.f / (1.f + __expf(-v));
}

// ---------------------------------------------------------------------------
// Kernel 1 (exact r1-bench version, proven 101.2/98.6): fused convert + MFMA
// bf16 GEMM + x->bf16 conversion.
//  left  (t<32):  -> LpT[b][i>>2][e][i&3] = C + b_lin[e]   (fp32 transposed)
//  right (32<=t<64): -> R2[b][(e>>3)*2048 + j*8 + (e&7)] = bf16(C)
//  conv  (t>=64): xbf = bf16(x)
// ---------------------------------------------------------------------------
__global__ __launch_bounds__(256) void mfma_gemm_kernel(
    const float* __restrict__ x,      // (8,256,256) x[b][w][k]
    const float* __restrict__ W,      // (512,512)
    const float* __restrict__ b_lin,  // (512)
    float* __restrict__ LpT,          // (8,64,512,4) fp32  L^T blocked
    unsigned short* __restrict__ R2,  // (8, 512e x 256j packed)
    unsigned short* __restrict__ xbf) // (8,256,256) bf16
{
    const int b = blockIdx.y;
    const int t = blockIdx.x;

    if (t >= 64) {   // ---- x -> bf16 straight conversion
        const int idx = b * 65536 + (t - 64) * 2048 + threadIdx.x * 8;
        const float4 v0 = *(const float4*)(x + idx);
        const float4 v1 = *(const float4*)(x + idx + 4);
        u16x8 o;
        o[0] = f2bf(v0.x); o[1] = f2bf(v0.y); o[2] = f2bf(v0.z); o[3] = f2bf(v0.w);
        o[4] = f2bf(v1.x); o[5] = f2bf(v1.y); o[6] = f2bf(v1.z); o[7] = f2bf(v1.w);
        *(u16x8*)(xbf + idx) = o;
        return;
    }

    const bool left = (t < 32);
    int m0, n0;
    if (left) { m0 = (t >> 3) * 64; n0 = (t & 7) * 64; }
    else      { const int tt = t - 32; m0 = (tt >> 2) * 64; n0 = (tt & 3) * 64; }

    __shared__ unsigned short As[64][72];
    __shared__ unsigned short Bs[64][72];

    unsigned short (*Ts)[72] = left ? As : Bs;   // x^T tile
    unsigned short (*Ds)[72] = left ? Bs : As;   // W tile
    const int cbase = left ? m0 : n0;            // x column base (k or j)
    const int rbase = left ? n0 : m0;            // W row base (e)
    const int coff  = left ? 0 : 256;            // W column offset

    const int tid  = threadIdx.x;
    const int wv   = tid >> 6;
    const int lane = tid & 63;
    const int wy = wv >> 1, wx = wv & 1;
    const int lr = lane & 15;
    const int lk = lane >> 4;

    const float* xb = x + b * 65536;

    f32x4 acc[2][2];
    #pragma unroll
    for (int i = 0; i < 2; i++)
        #pragma unroll
        for (int jj = 0; jj < 2; jj++) acc[i][jj] = (f32x4){0.f, 0.f, 0.f, 0.f};

    const int wl = tid >> 4;         // 0..15
    const int kg = tid & 15;         // 0..15
    const int dr = tid >> 2;         // 0..63
    const int dc = (tid & 3) * 16;

    for (int k0 = 0; k0 < 256; k0 += 64) {
        #pragma unroll
        for (int p = 0; p < 4; p++) {
            const int w = wl + 16 * p;
            const float4 v = *(const float4*)(xb + (k0 + w) * 256 + cbase + kg * 4);
            Ts[kg * 4 + 0][w] = f2bf(v.x);
            Ts[kg * 4 + 1][w] = f2bf(v.y);
            Ts[kg * 4 + 2][w] = f2bf(v.z);
            Ts[kg * 4 + 3][w] = f2bf(v.w);
        }
        {
            const float* src = W + (rbase + dr) * 512 + coff + k0 + dc;
            const float4 v0 = *(const float4*)(src);
            const float4 v1 = *(const float4*)(src + 4);
            const float4 v2 = *(const float4*)(src + 8);
            const float4 v3 = *(const float4*)(src + 12);
            u16x8 o0, o1;
            o0[0]=f2bf(v0.x); o0[1]=f2bf(v0.y); o0[2]=f2bf(v0.z); o0[3]=f2bf(v0.w);
            o0[4]=f2bf(v1.x); o0[5]=f2bf(v1.y); o0[6]=f2bf(v1.z); o0[7]=f2bf(v1.w);
            o1[0]=f2bf(v2.x); o1[1]=f2bf(v2.y); o1[2]=f2bf(v2.z); o1[3]=f2bf(v2.w);
            o1[4]=f2bf(v3.x); o1[5]=f2bf(v3.y); o1[6]=f2bf(v3.z); o1[7]=f2bf(v3.w);
            *(u16x8*)&Ds[dr][dc]     = o0;
            *(u16x8*)&Ds[dr][dc + 8] = o1;
        }
        __syncthreads();
        #pragma unroll
        for (int kk = 0; kk < 64; kk += 32) {
            const bf16x8 a0 = *(const bf16x8*)&As[wy * 32 + lr][kk + lk * 8];
            const bf16x8 a1 = *(const bf16x8*)&As[wy * 32 + 16 + lr][kk + lk * 8];
            const bf16x8 b0 = *(const bf16x8*)&Bs[wx * 32 + lr][kk + lk * 8];
            const bf16x8 b1 = *(const bf16x8*)&Bs[wx * 32 + 16 + lr][kk + lk * 8];
            acc[0][0] = __builtin_amdgcn_mfma_f32_16x16x32_bf16(a0, b0, acc[0][0], 0, 0, 0);
            acc[0][1] = __builtin_amdgcn_mfma_f32_16x16x32_bf16(a0, b1, acc[0][1], 0, 0, 0);
            acc[1][0] = __builtin_amdgcn_mfma_f32_16x16x32_bf16(a1, b0, acc[1][0], 0, 0, 0);
            acc[1][1] = __builtin_amdgcn_mfma_f32_16x16x32_bf16(a1, b1, acc[1][1], 0, 0, 0);
        }
        __syncthreads();
    }

    // C/D layout: col = lane&15, row = (lane>>4)*4 + reg
    if (left) {
        #pragma unroll
        for (int mi = 0; mi < 2; mi++) {
            #pragma unroll
            for (int ni = 0; ni < 2; ni++) {
                const int row = m0 + wy * 32 + mi * 16 + lk * 4;   // i (=k)
                const int col = n0 + wx * 32 + ni * 16 + lr;       // e
                const float bl = b_lin[col];
                float4 o;
                o.x = acc[mi][ni][0] + bl;
                o.y = acc[mi][ni][1] + bl;
                o.z = acc[mi][ni][2] + bl;
                o.w = acc[mi][ni][3] + bl;
                *(float4*)(LpT + b * 131072 + (row >> 2) * 2048 + col * 4) = o;
            }
        }
    } else {
        unsigned short* R2b = R2 + b * 131072;
        #pragma unroll
        for (int mi = 0; mi < 2; mi++) {
            #pragma unroll
            for (int ni = 0; ni < 2; ni++) {
                const int row = m0 + wy * 32 + mi * 16 + lk * 4;   // e base (4)
                const int col = n0 + wx * 32 + ni * 16 + lr;       // j
                ushort4 o;
                o.x = f2bf(acc[mi][ni][0]);
                o.y = f2bf(acc[mi][ni][1]);
                o.z = f2bf(acc[mi][ni][2]);
                o.w = f2bf(acc[mi][ni][3]);
                *(ushort4*)(R2b + (row >> 3) * 2048 + col * 8 + (row & 7)) = o;
            }
        }
    }
}

// ---------------------------------------------------------------------------
// Kernel 2 (r9 verbatim — best measured 98.56 total): r1 structure + two
// pure load-hoists. grid 512 = (i-tile of 4) x (b = blk&7); 1024 thr =
// 256 j x 4 e-quarters. L/a stream via wave-uniform global reads; R bf16
// stream, depth-2 prefetch; 2 block barriers.
// Hoists (proven +2.7us): (a) matvec x-fragments kt0..3 and (b) softmax bias
// loaded BEFORE the post-score barrier — L2 latency hides under barrier
// drain + softmax.
// score[i][j] = 0.6*(uL[i]+uR[j]) + 0.4*sum_e a[e]*|L[i,e]+R[e,j]| + bias
// ---------------------------------------------------------------------------
__global__ __launch_bounds__(1024, 8) void attn_kernel(
    const unsigned short* __restrict__ xbf,   // (8,256,256) bf16 x[b][w][j]
    const float* __restrict__ LpT,            // (8,64,512,4) fp32, b_lin folded
    const unsigned int* __restrict__ R2u,     // packed bf16 pairs
    const float* __restrict__ a,              // (512)
    const float* __restrict__ bias,           // (256,256)
    float* __restrict__ out)                  // (8,256,256)
{
    const int b     = blockIdx.x & 7;
    const int itile = blockIdx.x >> 3;        // 0..63
    const int i0    = itile * 4;
    const int tid   = threadIdx.x;
    const int j     = tid & 255;
    const int wv    = tid >> 6;               // 0..15
    const int lane  = tid & 63;

    __shared__ float acc2P[4][4][256];        // 16 KB  [e-quarter][i][j]
    __shared__ float rgp[4][256];             // 4 KB   [e-quarter][j]
    __shared__ float u15p[8][4];
    __shared__ unsigned short atbf[16 * 264]; // 8.25 KB (rows 4..15 unused)

    // wave-uniform e-quarter index (readfirstlane -> SGPR -> scalar loads)
    const int ehq = __builtin_amdgcn_readfirstlane(tid >> 8);  // 0..3

    // uniform stream bases
    const float* Lq = LpT + b * 131072 + itile * 2048 + ehq * 512;  // [e_loc][4]
    const float* aq = a + ehq * 128;
    const uint4* Rq = (const uint4*)(R2u + b * 65536) + (ehq * 16) * 256 + j;

    // ---- R prefetch, depth 2 (named regs, no dynamic indexing)
    uint4 rb0 = Rq[0];
    uint4 rb1 = Rq[256];

    // ---- uL partials: waves 0..7; waves 8..15 go straight to score
    if (tid < 512) {
        const float4 lv = *(const float4*)(LpT + b * 131072 + itile * 2048 + tid * 4);
        const float ae = a[tid];
        float p0 = ae * lv.x, p1 = ae * lv.y, p2 = ae * lv.z, p3 = ae * lv.w;
        #pragma unroll
        for (int off = 32; off; off >>= 1) {
            p0 += __shfl_xor(p0, off);
            p1 += __shfl_xor(p1, off);
            p2 += __shfl_xor(p2, off);
            p3 += __shfl_xor(p3, off);
        }
        if (lane == 0) {
            u15p[wv][0] = p0; u15p[wv][1] = p1;
            u15p[wv][2] = p2; u15p[wv][3] = p3;
        }
    }

    // ---- score: 128 e per thread (e-quarter), 4 i rows, uniform L/a loads
    float acc0 = 0.f, acc1 = 0.f, acc2 = 0.f, acc3 = 0.f, rsum = 0.f;

    #pragma unroll 2
    for (int tk = 0; tk < 16; tk++) {
        uint4 rb2;
        if (tk < 14) rb2 = Rq[(tk + 2) * 256];
        float r[8];
        r[0] = bf_lo(rb0.x); r[1] = bf_hi(rb0.x);
        r[2] = bf_lo(rb0.y); r[3] = bf_hi(rb0.y);
        r[4] = bf_lo(rb0.z); r[5] = bf_hi(rb0.z);
        r[6] = bf_lo(rb0.w); r[7] = bf_hi(rb0.w);
        #pragma unroll
        for (int g = 0; g < 2; g++) {
            const float4 av4 = *(const float4*)(aq + tk * 8 + g * 4);
            const float4 l0 = *(const float4*)(Lq + (tk * 8 + g * 4 + 0) * 4);
            const float4 l1 = *(const float4*)(Lq + (tk * 8 + g * 4 + 1) * 4);
            const float4 l2 = *(const float4*)(Lq + (tk * 8 + g * 4 + 2) * 4);
            const float4 l3 = *(const float4*)(Lq + (tk * 8 + g * 4 + 3) * 4);
            const float rv0 = r[g * 4 + 0];
            const float rv1 = r[g * 4 + 1];
            const float rv2 = r[g * 4 + 2];
            const float rv3 = r[g * 4 + 3];
            rsum = fmaf(av4.x, rv0, rsum);
            acc0 = fmaf(av4.x, fabsf(l0.x + rv0), acc0);
            acc1 = fmaf(av4.x, fabsf(l0.y + rv0), acc1);
            acc2 = fmaf(av4.x, fabsf(l0.z + rv0), acc2);
            acc3 = fmaf(av4.x, fabsf(l0.w + rv0), acc3);
            rsum = fmaf(av4.y, rv1, rsum);
            acc0 = fmaf(av4.y, fabsf(l1.x + rv1), acc0);
            acc1 = fmaf(av4.y, fabsf(l1.y + rv1), acc1);
            acc2 = fmaf(av4.y, fabsf(l1.z + rv1), acc2);
            acc3 = fmaf(av4.y, fabsf(l1.w + rv1), acc3);
            rsum = fmaf(av4.z, rv2, rsum);
            acc0 = fmaf(av4.z, fabsf(l2.x + rv2), acc0);
            acc1 = fmaf(av4.z, fabsf(l2.y + rv2), acc1);
            acc2 = fmaf(av4.z, fabsf(l2.z + rv2), acc2);
            acc3 = fmaf(av4.z, fabsf(l2.w + rv2), acc3);
            rsum = fmaf(av4.w, rv3, rsum);
            acc0 = fmaf(av4.w, fabsf(l3.x + rv3), acc0);
            acc1 = fmaf(av4.w, fabsf(l3.y + rv3), acc1);
            acc2 = fmaf(av4.w, fabsf(l3.z + rv3), acc2);
            acc3 = fmaf(av4.w, fabsf(l3.w + rv3), acc3);
        }
        rb0 = rb1;
        rb1 = rb2;
    }
    acc2P[ehq][0][j] = acc0;
    acc2P[ehq][1][j] = acc1;
    acc2P[ehq][2][j] = acc2;
    acc2P[ehq][3][j] = acc3;
    rgp[ehq][j] = rsum;

    // ---- (a) hoist matvec x-fragment loads (kt 0..3) above the barrier:
    // latency hides under barrier drain + softmax. Same addresses as before.
    const int lr = lane & 15;
    const int lk = lane >> 4;
    const unsigned short* xw = xbf + b * 65536 + (wv * 16 + lr) * 256;
    const bf16x8 px0 = *(const bf16x8*)(xw + 0 * 32 + lk * 8);
    const bf16x8 px1 = *(const bf16x8*)(xw + 1 * 32 + lk * 8);
    const bf16x8 px2 = *(const bf16x8*)(xw + 2 * 32 + lk * 8);
    const bf16x8 px3 = *(const bf16x8*)(xw + 3 * 32 + lk * 8);

    // ---- (b) hoist softmax bias loads above the barrier
    float bs0 = 0.f, bs1 = 0.f, bs2 = 0.f, bs3 = 0.f;
    if (wv < 4) {
        const float* brow = bias + (i0 + wv) * 256 + lane;
        bs0 = brow[0];
        bs1 = brow[64];
        bs2 = brow[128];
        bs3 = brow[192];
    }
    __syncthreads();

    // ---- softmax (combine folded in): wave i (wv<4) -> row i
    if (wv < 4) {
        const int i = wv;
        float u15 = 0.f;
        #pragma unroll
        for (int q = 0; q < 8; q++) u15 += u15p[q][i];   // LDS broadcast reads
        u15 *= 0.6f;
        float v[4];
        const float bsv[4] = { bs0, bs1, bs2, bs3 };
        float m = -1e30f;
        #pragma unroll
        for (int u = 0; u < 4; u++) {
            const int jj = lane + 64 * u;
            const float uR = rgp[0][jj] + rgp[1][jj] + rgp[2][jj] + rgp[3][jj];
            const float ab = acc2P[0][i][jj] + acc2P[1][i][jj]
                           + acc2P[2][i][jj] + acc2P[3][i][jj];
            v[u] = u15 + 0.6f * uR + 0.4f * ab + bsv[u];
            m = fmaxf(m, v[u]);
        }
        #pragma unroll
        for (int off = 32; off; off >>= 1) m = fmaxf(m, __shfl_xor(m, off));
        float ssum = 0.f;
        #pragma unroll
        for (int u = 0; u < 4; u++) { v[u] = __expf(v[u] - m); ssum += v[u]; }
        #pragma unroll
        for (int off = 32; off; off >>= 1) ssum += __shfl_xor(ssum, off);
        const float inv = 1.f / ssum;
        #pragma unroll
        for (int u = 0; u < 4; u++)
            atbf[i * 264 + lane + 64 * u] = f2bf(v[u] * inv);
    }
    __syncthreads();

    // ---- matvec via MFMA: D[i][w] = sum_j attn[i][j] * x[b][w][j]
    // 16 waves; wave wv handles w-tile wv. atbf rows 4..15 are garbage LDS
    // but only pollute D rows 4..15, which are never stored (lk==0 only).
    // kt 0..3 use the pre-barrier-loaded px fragments.
    {
        f32x4 hacc = (f32x4){0.f, 0.f, 0.f, 0.f};
        const bf16x8 a0 = *(const bf16x8*)&atbf[lr * 264 + 0 * 32 + lk * 8];
        hacc = __builtin_amdgcn_mfma_f32_16x16x32_bf16(a0, px0, hacc, 0, 0, 0);
        const bf16x8 a1 = *(const bf16x8*)&atbf[lr * 264 + 1 * 32 + lk * 8];
        hacc = __builtin_amdgcn_mfma_f32_16x16x32_bf16(a1, px1, hacc, 0, 0, 0);
        const bf16x8 a2 = *(const bf16x8*)&atbf[lr * 264 + 2 * 32 + lk * 8];
        hacc = __builtin_amdgcn_mfma_f32_16x16x32_bf16(a2, px2, hacc, 0, 0, 0);
        const bf16x8 a3 = *(const bf16x8*)&atbf[lr * 264 + 3 * 32 + lk * 8];
        hacc = __builtin_amdgcn_mfma_f32_16x16x32_bf16(a3, px3, hacc, 0, 0, 0);
        #pragma unroll
        for (int kt = 4; kt < 8; kt++) {
            const bf16x8 av = *(const bf16x8*)&atbf[lr * 264 + kt * 32 + lk * 8];
            const bf16x8 bv = *(const bf16x8*)(xw + kt * 32 + lk * 8);
            hacc = __builtin_amdgcn_mfma_f32_16x16x32_bf16(av, bv, hacc, 0, 0, 0);
        }
        if (lk == 0) {
            float4 o;
            o.x = sigmoidf_(hacc[0]);
            o.y = sigmoidf_(hacc[1]);
            o.z = sigmoidf_(hacc[2]);
            o.w = sigmoidf_(hacc[3]);
            *(float4*)(out + b * 65536 + (wv * 16 + lr) * 256 + i0) = o;
        }
    }
}

extern "C" void kernel_launch(void* const* d_in, const int* in_sizes, int n_in,
                              void* d_out, int out_size, void* d_ws, size_t ws_size,
                              hipStream_t stream) {
    const float* x     = (const float*)d_in[0];
    const float* W     = (const float*)d_in[1];
    const float* b_lin = (const float*)d_in[2];
    const float* a     = (const float*)d_in[3];
    const float* bias  = (const float*)d_in[4];
    float* out = (float*)d_out;

    char* ws = (char*)d_ws;
    float*          LpT = (float*)ws;                          // 4 MB
    unsigned short* R2  = (unsigned short*)(ws + (4 << 20));   // 2 MB
    unsigned short* xbf = (unsigned short*)(ws + (6 << 20));   // 1 MB

    mfma_gemm_kernel<<<dim3(96, 8), 256, 0, stream>>>(x, W, b_lin, LpT, R2, xbf);
    attn_kernel<<<512, 1024, 0, stream>>>(xbf, LpT, (const unsigned int*)R2,
                                          a, bias, out);
}